// Round 1
// baseline (43.501 us; speedup 1.0000x reference)
//
#include <hip/hip_runtime.h>
#include <math.h>

#define NSZ 512
#define MSZ 256
#define NPIX (6 * NSZ * NSZ)                      // 1,572,864 vertices
#define NQ   ((NSZ - 1) * (NSZ - 1))              // 261,121 quads per cube face
#define NFACE (6 * 2 * NQ)                        // 3,133,452 triangles

// ---------------------------------------------------------------------------
// Kernel A: vert = bilinear(vrt, 256->512) + 0.5*sigmoid(ps)*|bilinear(nrm)|
// out layout: (1, 6*N*N, 3) -> out0[v*3 + c], v = f*N*N + y*N + x
// input layout: (1, 6*M*M, 3) -> in[(f*M*M + i*M + j)*3 + c]
// ---------------------------------------------------------------------------
__global__ __launch_bounds__(256) void k_vert(const float* __restrict__ vrt,
                                              const float* __restrict__ nrm,
                                              const float* __restrict__ ps,
                                              float* __restrict__ out0) {
    int v = blockIdx.x * blockDim.x + threadIdx.x;
    if (v >= NPIX) return;
    int f   = v >> 18;                 // / (512*512)
    int rem = v & (NSZ * NSZ - 1);
    int y   = rem >> 9;
    int x   = rem & (NSZ - 1);

    const float scale = 255.0f / 511.0f;   // linspace(0, M-1, N) step
    float cy = (float)y * scale;
    float cx = (float)x * scale;
    int iy0 = (int)floorf(cy); iy0 = iy0 < 0 ? 0 : (iy0 > MSZ - 1 ? MSZ - 1 : iy0);
    int ix0 = (int)floorf(cx); ix0 = ix0 < 0 ? 0 : (ix0 > MSZ - 1 ? MSZ - 1 : ix0);
    int iy1 = min(iy0 + 1, MSZ - 1);
    int ix1 = min(ix0 + 1, MSZ - 1);
    float wy = cy - (float)iy0;
    float wx = cx - (float)ix0;
    float w00 = (1.0f - wy) * (1.0f - wx);
    float w01 = (1.0f - wy) * wx;
    float w10 = wy * (1.0f - wx);
    float w11 = wy * wx;

    int fb  = f * (MSZ * MSZ);
    int i00 = (fb + iy0 * MSZ + ix0) * 3;
    int i01 = (fb + iy0 * MSZ + ix1) * 3;
    int i10 = (fb + iy1 * MSZ + ix0) * 3;
    int i11 = (fb + iy1 * MSZ + ix1) * 3;

    float vs[3], ns[3];
#pragma unroll
    for (int c = 0; c < 3; ++c) {
        vs[c] = vrt[i00 + c] * w00 + vrt[i01 + c] * w01 +
                vrt[i10 + c] * w10 + vrt[i11 + c] * w11;
        ns[c] = nrm[i00 + c] * w00 + nrm[i01 + c] * w01 +
                nrm[i10 + c] * w10 + nrm[i11 + c] * w11;
    }
    float mag = sqrtf(ns[0] * ns[0] + ns[1] * ns[1] + ns[2] * ns[2]);
    float sig = 1.0f / (1.0f + expf(-ps[v]));   // ps layout (6,1,N,N) == v order
    float add = 0.5f * sig * mag;

    out0[v * 3 + 0] = vs[0] + add;
    out0[v * 3 + 1] = vs[1] + add;
    out0[v * 3 + 2] = vs[2] + add;
}

// ---------------------------------------------------------------------------
// Kernel B: faces indices (written as float values; exact below 2^24)
// per cube face s: first NQ tris (a,b,c), then NQ tris (b,d,c)
// ---------------------------------------------------------------------------
__global__ __launch_bounds__(256) void k_faces(float* __restrict__ out1) {
    int t = blockIdx.x * blockDim.x + threadIdx.x;
    if (t >= NFACE) return;
    int s  = t / (2 * NQ);
    int r0 = t - s * (2 * NQ);
    int ty = r0 / NQ;
    int qi = r0 - ty * NQ;
    int R  = qi / (NSZ - 1);
    int Q  = qi - R * (NSZ - 1);
    int base = s * (NSZ * NSZ);
    int a = base + R * NSZ + Q;
    int b = a + 1;
    int c = a + NSZ;
    int d = c + 1;
    int i0, i1, i2;
    if (ty == 0) { i0 = a; i1 = b; i2 = c; }
    else         { i0 = b; i1 = d; i2 = c; }
    out1[t * 3 + 0] = (float)i0;
    out1[t * 3 + 1] = (float)i1;
    out1[t * 3 + 2] = (float)i2;
}

// ---------------------------------------------------------------------------
// Kernel C: vertex normals by gather — each vertex sums the unit normals of
// its <=6 adjacent triangles, normalizes, applies per-cube-face sign.
// ---------------------------------------------------------------------------
struct F3 { float x, y, z; };

__device__ inline void tri_acc(bool ok, const F3& A, const F3& B, const F3& C,
                               float& ax, float& ay, float& az) {
    if (!ok) return;
    float e1x = B.x - A.x, e1y = B.y - A.y, e1z = B.z - A.z;
    float e2x = C.x - A.x, e2y = C.y - A.y, e2z = C.z - A.z;
    float nx = e1y * e2z - e1z * e2y;
    float ny = e1z * e2x - e1x * e2z;
    float nz = e1x * e2y - e1y * e2x;
    float nn = sqrtf(nx * nx + ny * ny + nz * nz);
    float inv = 1.0f / fmaxf(nn, 1e-12f);
    ax += nx * inv; ay += ny * inv; az += nz * inv;
}

__global__ __launch_bounds__(256) void k_normals(const float* __restrict__ vert,
                                                 float* __restrict__ out2) {
    int v = blockIdx.x * blockDim.x + threadIdx.x;
    if (v >= NPIX) return;
    int f   = v >> 18;
    int rem = v & (NSZ * NSZ - 1);
    int r   = rem >> 9;
    int q   = rem & (NSZ - 1);

    int fb = f * (NSZ * NSZ);
    auto P = [&](int rr, int qq) {
        int i = (fb + rr * NSZ + qq) * 3;
        F3 p; p.x = vert[i]; p.y = vert[i + 1]; p.z = vert[i + 2];
        return p;
    };

    bool rm = (r > 0), rp = (r < NSZ - 1), qm = (q > 0), qp = (q < NSZ - 1);

    F3 p     = P(r, q);
    F3 pqm   = qm ? P(r, q - 1) : p;
    F3 pqp   = qp ? P(r, q + 1) : p;
    F3 prm   = rm ? P(r - 1, q) : p;
    F3 prp   = rp ? P(r + 1, q) : p;
    F3 prmqp = (rm && qp) ? P(r - 1, q + 1) : p;
    F3 prpqm = (rp && qm) ? P(r + 1, q - 1) : p;

    float ax = 0.0f, ay = 0.0f, az = 0.0f;
    // tri0(r,q):      (a,b,c) = (P(r,q),   P(r,q+1),   P(r+1,q))
    tri_acc(rp && qp, p,     pqp,   prp,   ax, ay, az);
    // tri0(r,q-1):    (P(r,q-1), P(r,q),  P(r+1,q-1))
    tri_acc(rp && qm, pqm,   p,     prpqm, ax, ay, az);
    // tri0(r-1,q):    (P(r-1,q), P(r-1,q+1), P(r,q))
    tri_acc(rm && qp, prm,   prmqp, p,     ax, ay, az);
    // tri1(r,q-1):    (b,d,c) = (P(r,q), P(r+1,q), P(r+1,q-1))
    tri_acc(rp && qm, p,     prp,   prpqm, ax, ay, az);
    // tri1(r-1,q-1):  (P(r-1,q), P(r,q), P(r,q-1))
    tri_acc(rm && qm, prm,   p,     pqm,   ax, ay, az);
    // tri1(r-1,q):    (P(r-1,q+1), P(r,q+1), P(r,q))
    tri_acc(rm && qp, prmqp, pqp,   p,     ax, ay, az);

    float nn  = sqrtf(ax * ax + ay * ay + az * az);
    float inv = 1.0f / fmaxf(nn, 1e-12f);
    // sign = [-1, 1, 1, -1, -1, 1]
    float sg = (f == 1 || f == 2 || f == 5) ? 1.0f : -1.0f;
    out2[v * 3 + 0] = ax * inv * sg;
    out2[v * 3 + 1] = ay * inv * sg;
    out2[v * 3 + 2] = az * inv * sg;
}

extern "C" void kernel_launch(void* const* d_in, const int* in_sizes, int n_in,
                              void* d_out, int out_size, void* d_ws, size_t ws_size,
                              hipStream_t stream) {
    const float* vrt = (const float*)d_in[0];
    const float* nrm = (const float*)d_in[1];
    const float* ps  = (const float*)d_in[2];
    // d_in[3] = faces (int32) — regenerated on device, not read.

    float* out0 = (float*)d_out;                 // vert:    6*512*512*3
    float* out1 = out0 + (size_t)NPIX * 3;       // faces:   NFACE*3
    float* out2 = out1 + (size_t)NFACE * 3;      // normals: 6*512*512*3

    const int B = 256;
    k_vert<<<(NPIX + B - 1) / B, B, 0, stream>>>(vrt, nrm, ps, out0);
    k_faces<<<(NFACE + B - 1) / B, B, 0, stream>>>(out1);
    k_normals<<<(NPIX + B - 1) / B, B, 0, stream>>>(out0, out2);
}

// Round 2
// 39.031 us; speedup vs baseline: 1.1145x; 1.1145x over previous
//
#include <hip/hip_runtime.h>
#include <math.h>

#define NSZ 512
#define MSZ 256
#define NPIX (6 * NSZ * NSZ)                      // 1,572,864 vertices
#define NQ   ((NSZ - 1) * (NSZ - 1))              // 261,121 quads per cube face
#define NFACE (6 * 2 * NQ)                        // 3,133,452 triangles
#define TS 32                                     // output tile
#define HS (TS + 2)                               // tile + halo = 34

// ---------------------------------------------------------------------------
// Bilinear sample (align-corners 256->512) of vrt & nrm at (y,x), plus the
// sigmoid(ps) displacement.  Deterministic per (f,y,x) -> tiles agree exactly.
// ---------------------------------------------------------------------------
__device__ inline void sample_vert(const float* __restrict__ vrt,
                                   const float* __restrict__ nrm,
                                   const float* __restrict__ ps,
                                   int f, int y, int x, float out[3]) {
    const float scale = 255.0f / 511.0f;
    float cy = (float)y * scale;
    float cx = (float)x * scale;
    int iy0 = (int)floorf(cy); iy0 = iy0 < 0 ? 0 : (iy0 > MSZ - 1 ? MSZ - 1 : iy0);
    int ix0 = (int)floorf(cx); ix0 = ix0 < 0 ? 0 : (ix0 > MSZ - 1 ? MSZ - 1 : ix0);
    int iy1 = min(iy0 + 1, MSZ - 1);
    int ix1 = min(ix0 + 1, MSZ - 1);
    float wy = cy - (float)iy0;
    float wx = cx - (float)ix0;
    float w00 = (1.0f - wy) * (1.0f - wx);
    float w01 = (1.0f - wy) * wx;
    float w10 = wy * (1.0f - wx);
    float w11 = wy * wx;

    int fb  = f * (MSZ * MSZ);
    int i00 = (fb + iy0 * MSZ + ix0) * 3;
    int i01 = (fb + iy0 * MSZ + ix1) * 3;
    int i10 = (fb + iy1 * MSZ + ix0) * 3;
    int i11 = (fb + iy1 * MSZ + ix1) * 3;

    float vs[3], ns[3];
#pragma unroll
    for (int c = 0; c < 3; ++c) {
        vs[c] = vrt[i00 + c] * w00 + vrt[i01 + c] * w01 +
                vrt[i10 + c] * w10 + vrt[i11 + c] * w11;
        ns[c] = nrm[i00 + c] * w00 + nrm[i01 + c] * w01 +
                nrm[i10 + c] * w10 + nrm[i11 + c] * w11;
    }
    float mag = sqrtf(ns[0] * ns[0] + ns[1] * ns[1] + ns[2] * ns[2]);
    float sig = 1.0f / (1.0f + expf(-ps[f * (NSZ * NSZ) + y * NSZ + x]));
    float add = 0.5f * sig * mag;
    out[0] = vs[0] + add;
    out[1] = vs[1] + add;
    out[2] = vs[2] + add;
}

__device__ inline void tri_acc(bool ok,
                               float Ax, float Ay, float Az,
                               float Bx, float By, float Bz,
                               float Cx, float Cy, float Cz,
                               float& ax, float& ay, float& az) {
    if (!ok) return;
    float e1x = Bx - Ax, e1y = By - Ay, e1z = Bz - Az;
    float e2x = Cx - Ax, e2y = Cy - Ay, e2z = Cz - Az;
    float nx = e1y * e2z - e1z * e2y;
    float ny = e1z * e2x - e1x * e2z;
    float nz = e1x * e2y - e1y * e2x;
    float nn = sqrtf(nx * nx + ny * ny + nz * nz);
    float inv = 1.0f / fmaxf(nn, 1e-12f);
    ax += nx * inv; ay += ny * inv; az += nz * inv;
}

// ---------------------------------------------------------------------------
// Fused kernel: per 32x32 tile, compute 34x34 halo of verts into LDS (and
// write the interior to out0), then compute vertex normals from LDS -> out2.
// 6 faces * 16*16 tiles = 1536 blocks.
// ---------------------------------------------------------------------------
__global__ __launch_bounds__(256) void k_vert_norm(const float* __restrict__ vrt,
                                                   const float* __restrict__ nrm,
                                                   const float* __restrict__ ps,
                                                   float* __restrict__ out0,
                                                   float* __restrict__ out2) {
    __shared__ float sv[HS * HS * 3];    // 13,872 B

    int blk = blockIdx.x;
    int f   = blk >> 8;
    int t   = blk & 255;
    int tr  = (t >> 4) * TS;             // tile origin row
    int tq  = (t & 15) * TS;             // tile origin col

    // ---- phase 1: fill halo tile (clamped coords at face edges) ----
    for (int p = threadIdx.x; p < HS * HS; p += 256) {
        int pr = p / HS, pq = p - pr * HS;
        int y = tr + pr - 1, x = tq + pq - 1;
        int yc = min(max(y, 0), NSZ - 1);
        int xc = min(max(x, 0), NSZ - 1);
        float val[3];
        sample_vert(vrt, nrm, ps, f, yc, xc, val);
        sv[p * 3 + 0] = val[0];
        sv[p * 3 + 1] = val[1];
        sv[p * 3 + 2] = val[2];
        if (pr >= 1 && pr <= TS && pq >= 1 && pq <= TS) {
            int gi = (f * (NSZ * NSZ) + y * NSZ + x) * 3;
            out0[gi + 0] = val[0];
            out0[gi + 1] = val[1];
            out0[gi + 2] = val[2];
        }
    }
    __syncthreads();

    // ---- phase 2: normals for the 32x32 interior ----
    for (int p = threadIdx.x; p < TS * TS; p += 256) {
        int r = p >> 5, q = p & 31;          // local in-tile coords
        int gy = tr + r, gx = tq + q;        // global in-face coords
        bool rm = (gy > 0), rp = (gy < NSZ - 1), qm = (gx > 0), qp = (gx < NSZ - 1);

        int lr = r + 1, lq = q + 1;
        #define LV(rr, qq, c) sv[(((rr) * HS) + (qq)) * 3 + (c)]
        float px    = LV(lr, lq, 0),     py    = LV(lr, lq, 1),     pz    = LV(lr, lq, 2);
        float qmx   = LV(lr, lq-1, 0),   qmy   = LV(lr, lq-1, 1),   qmz   = LV(lr, lq-1, 2);
        float qpx   = LV(lr, lq+1, 0),   qpy   = LV(lr, lq+1, 1),   qpz   = LV(lr, lq+1, 2);
        float rmx   = LV(lr-1, lq, 0),   rmy   = LV(lr-1, lq, 1),   rmz   = LV(lr-1, lq, 2);
        float rpx   = LV(lr+1, lq, 0),   rpy   = LV(lr+1, lq, 1),   rpz   = LV(lr+1, lq, 2);
        float rmqpx = LV(lr-1, lq+1, 0), rmqpy = LV(lr-1, lq+1, 1), rmqpz = LV(lr-1, lq+1, 2);
        float rpqmx = LV(lr+1, lq-1, 0), rpqmy = LV(lr+1, lq-1, 1), rpqmz = LV(lr+1, lq-1, 2);
        #undef LV

        float ax = 0.0f, ay = 0.0f, az = 0.0f;
        // tri0(r,q):     (P(r,q),     P(r,q+1),   P(r+1,q))
        tri_acc(rp && qp, px, py, pz,       qpx, qpy, qpz,    rpx, rpy, rpz,    ax, ay, az);
        // tri0(r,q-1):   (P(r,q-1),   P(r,q),     P(r+1,q-1))
        tri_acc(rp && qm, qmx, qmy, qmz,    px, py, pz,       rpqmx, rpqmy, rpqmz, ax, ay, az);
        // tri0(r-1,q):   (P(r-1,q),   P(r-1,q+1), P(r,q))
        tri_acc(rm && qp, rmx, rmy, rmz,    rmqpx, rmqpy, rmqpz, px, py, pz,    ax, ay, az);
        // tri1(r,q-1):   (P(r,q),     P(r+1,q),   P(r+1,q-1))
        tri_acc(rp && qm, px, py, pz,       rpx, rpy, rpz,    rpqmx, rpqmy, rpqmz, ax, ay, az);
        // tri1(r-1,q-1): (P(r-1,q),   P(r,q),     P(r,q-1))
        tri_acc(rm && qm, rmx, rmy, rmz,    px, py, pz,       qmx, qmy, qmz,    ax, ay, az);
        // tri1(r-1,q):   (P(r-1,q+1), P(r,q+1),   P(r,q))
        tri_acc(rm && qp, rmqpx, rmqpy, rmqpz, qpx, qpy, qpz, px, py, pz,       ax, ay, az);

        float nn  = sqrtf(ax * ax + ay * ay + az * az);
        float inv = 1.0f / fmaxf(nn, 1e-12f);
        float sg  = (f == 1 || f == 2 || f == 5) ? 1.0f : -1.0f;
        int gi = (f * (NSZ * NSZ) + gy * NSZ + gx) * 3;
        out2[gi + 0] = ax * inv * sg;
        out2[gi + 1] = ay * inv * sg;
        out2[gi + 2] = az * inv * sg;
    }
}

// ---------------------------------------------------------------------------
// Faces: one thread per 4 consecutive flat floats -> aligned dwordx4 stores.
// flat index o -> tri = o/3, comp = o%3; tri -> (s, ty, R, Q).
// ---------------------------------------------------------------------------
#define F3TOT (NFACE * 3)                 // 9,400,356 (divisible by 4)

__global__ __launch_bounds__(256) void k_faces4(float4* __restrict__ out1) {
    int t = blockIdx.x * blockDim.x + threadIdx.x;
    if (t >= F3TOT / 4) return;
    int o = t * 4;
    float vals[4];
#pragma unroll
    for (int k = 0; k < 4; ++k) {
        unsigned idx = (unsigned)(o + k);
        unsigned ti  = idx / 3u;
        unsigned c   = idx - ti * 3u;
        unsigned s   = ti / (2u * NQ);
        unsigned r1  = ti - s * (2u * NQ);
        unsigned ty  = r1 / NQ;
        unsigned qi  = r1 - ty * NQ;
        unsigned R   = qi / (NSZ - 1);
        unsigned Q   = qi - R * (NSZ - 1);
        unsigned a   = s * (NSZ * NSZ) + R * NSZ + Q;
        unsigned sel;
        if (c == 0)      sel = ty ? 1u : 0u;
        else if (c == 1) sel = ty ? (NSZ + 1u) : 1u;
        else             sel = NSZ;
        vals[k] = (float)(a + sel);
    }
    out1[t] = make_float4(vals[0], vals[1], vals[2], vals[3]);
}

extern "C" void kernel_launch(void* const* d_in, const int* in_sizes, int n_in,
                              void* d_out, int out_size, void* d_ws, size_t ws_size,
                              hipStream_t stream) {
    const float* vrt = (const float*)d_in[0];
    const float* nrm = (const float*)d_in[1];
    const float* ps  = (const float*)d_in[2];

    float* out0 = (float*)d_out;                 // vert:    6*512*512*3
    float* out1 = out0 + (size_t)NPIX * 3;       // faces:   NFACE*3
    float* out2 = out1 + (size_t)NFACE * 3;      // normals: 6*512*512*3

    k_vert_norm<<<6 * 16 * 16, 256, 0, stream>>>(vrt, nrm, ps, out0, out2);
    k_faces4<<<(F3TOT / 4 + 255) / 256, 256, 0, stream>>>((float4*)out1);
}

// Round 3
// 29.109 us; speedup vs baseline: 1.4944x; 1.3409x over previous
//
#include <hip/hip_runtime.h>
#include <math.h>

#define NSZ 512
#define MSZ 256
#define NPIX (6 * NSZ * NSZ)                      // 1,572,864 vertices
#define NQ   ((NSZ - 1) * (NSZ - 1))              // 261,121 quads per cube face
#define NFACE (6 * 2 * NQ)                        // 3,133,452 triangles
#define F3TOT (NFACE * 3)                         // 9,400,356 floats
#define TS 32                                     // output tile
#define HS (TS + 2)                               // vert halo = 34
#define QS (TS + 1)                               // quad halo = 33
#define NVB (6 * 16 * 16)                         // 1536 vert/normal blocks
#define NFT (F3TOT / 4)                           // 2,350,089 faces threads
#define NFB ((NFT + 255) / 256)                   // faces blocks

// ---- fast math helpers (raw HW op + 1 Newton step, rel err ~1e-7) --------
__device__ inline float fast_rcp(float x) {
    float r = __builtin_amdgcn_rcpf(x);
    return r * (2.0f - x * r);
}
__device__ inline float fast_rsqrt(float d) {       // d > 0
    float r = __builtin_amdgcn_rsqf(d);
    return r * (1.5f - 0.5f * d * r * r);
}
__device__ inline float fast_sigmoid(float x) {
    float e = __builtin_amdgcn_exp2f(-1.442695040888963f * x);
    return fast_rcp(1.0f + e);
}

// ---------------------------------------------------------------------------
// Bilinear sample (align-corners 256->512) of vrt & nrm at (y,x), plus the
// sigmoid(ps) displacement.  Deterministic per (f,y,x) -> tiles agree exactly.
// ---------------------------------------------------------------------------
__device__ inline void sample_vert(const float* __restrict__ vrt,
                                   const float* __restrict__ nrm,
                                   const float* __restrict__ ps,
                                   int f, int y, int x, float out[3]) {
    const float scale = 255.0f / 511.0f;
    float cy = (float)y * scale;
    float cx = (float)x * scale;
    int iy0 = (int)floorf(cy); iy0 = iy0 < 0 ? 0 : (iy0 > MSZ - 1 ? MSZ - 1 : iy0);
    int ix0 = (int)floorf(cx); ix0 = ix0 < 0 ? 0 : (ix0 > MSZ - 1 ? MSZ - 1 : ix0);
    int iy1 = min(iy0 + 1, MSZ - 1);
    int ix1 = min(ix0 + 1, MSZ - 1);
    float wy = cy - (float)iy0;
    float wx = cx - (float)ix0;
    float w00 = (1.0f - wy) * (1.0f - wx);
    float w01 = (1.0f - wy) * wx;
    float w10 = wy * (1.0f - wx);
    float w11 = wy * wx;

    int fb  = f * (MSZ * MSZ);
    int i00 = (fb + iy0 * MSZ + ix0) * 3;
    int i01 = (fb + iy0 * MSZ + ix1) * 3;
    int i10 = (fb + iy1 * MSZ + ix0) * 3;
    int i11 = (fb + iy1 * MSZ + ix1) * 3;

    float vs[3], ns[3];
#pragma unroll
    for (int c = 0; c < 3; ++c) {
        vs[c] = vrt[i00 + c] * w00 + vrt[i01 + c] * w01 +
                vrt[i10 + c] * w10 + vrt[i11 + c] * w11;
        ns[c] = nrm[i00 + c] * w00 + nrm[i01 + c] * w01 +
                nrm[i10 + c] * w10 + nrm[i11 + c] * w11;
    }
    float d2  = ns[0] * ns[0] + ns[1] * ns[1] + ns[2] * ns[2];
    float mag = __builtin_amdgcn_sqrtf(d2);
    float sig = fast_sigmoid(ps[f * (NSZ * NSZ) + y * NSZ + x]);
    float add = 0.5f * sig * mag;
    out[0] = vs[0] + add;
    out[1] = vs[1] + add;
    out[2] = vs[2] + add;
}

// ---------------------------------------------------------------------------
// One fused dispatch.
//  blocks [0, NVB):          vert + normals, one 32x32 tile each
//  blocks [NVB, NVB+NFB):    faces index stream (float4 stores)
// ---------------------------------------------------------------------------
__global__ __launch_bounds__(256) void k_all(const float* __restrict__ vrt,
                                             const float* __restrict__ nrm,
                                             const float* __restrict__ ps,
                                             float* __restrict__ out0,
                                             float* __restrict__ out1_f4,
                                             float* __restrict__ out2) {
    __shared__ float sv[HS * HS * 3];        // 13,872 B  verts (halo)
    __shared__ float tn0[QS * QS * 3];       // 13,068 B  tri0 unit normals
    __shared__ float tn1[QS * QS * 3];       // 13,068 B  tri1 unit normals

    int blk = blockIdx.x;

    if (blk >= NVB) {
        // ---------------- faces path: pure write stream ----------------
        int t = (blk - NVB) * 256 + threadIdx.x;
        if (t >= NFT) return;
        int o = t * 4;
        float vals[4];
#pragma unroll
        for (int k = 0; k < 4; ++k) {
            unsigned idx = (unsigned)(o + k);
            unsigned ti  = idx / 3u;
            unsigned c   = idx - ti * 3u;
            unsigned s   = ti / (2u * NQ);
            unsigned r1  = ti - s * (2u * NQ);
            unsigned ty  = r1 / NQ;
            unsigned qi  = r1 - ty * NQ;
            unsigned R   = qi / (NSZ - 1);
            unsigned Q   = qi - R * (NSZ - 1);
            unsigned a   = s * (NSZ * NSZ) + R * NSZ + Q;
            unsigned sel;
            if (c == 0)      sel = ty ? 1u : 0u;
            else if (c == 1) sel = ty ? (NSZ + 1u) : 1u;
            else             sel = NSZ;
            vals[k] = (float)(a + sel);
        }
        ((float4*)out1_f4)[t] = make_float4(vals[0], vals[1], vals[2], vals[3]);
        return;
    }

    // ---------------- vert + normals path ----------------
    int f  = blk >> 8;
    int t  = blk & 255;
    int tr = (t >> 4) * TS;              // tile origin row
    int tq = (t & 15) * TS;              // tile origin col

    // phase 1: 34x34 halo of displaced verts -> LDS (+ write interior)
    for (int p = threadIdx.x; p < HS * HS; p += 256) {
        int pr = p / HS, pq = p - pr * HS;
        int y = tr + pr - 1, x = tq + pq - 1;
        int yc = min(max(y, 0), NSZ - 1);
        int xc = min(max(x, 0), NSZ - 1);
        float val[3];
        sample_vert(vrt, nrm, ps, f, yc, xc, val);
        sv[p * 3 + 0] = val[0];
        sv[p * 3 + 1] = val[1];
        sv[p * 3 + 2] = val[2];
        if (pr >= 1 && pr <= TS && pq >= 1 && pq <= TS) {
            int gi = (f * (NSZ * NSZ) + y * NSZ + x) * 3;
            out0[gi + 0] = val[0];
            out0[gi + 1] = val[1];
            out0[gi + 2] = val[2];
        }
    }
    __syncthreads();

    // phase 1.5: unit normals of the 33x33 quad-halo's 2 tris each, once.
    // quad (Ri,Qi) uses sv corners (Ri,Qi),(Ri,Qi+1),(Ri+1,Qi),(Ri+1,Qi+1);
    // global quad row = tr+Ri-1, col = tq+Qi-1; invalid => zero (degenerate
    // by construction anyway, masked for safety).
    for (int p = threadIdx.x; p < QS * QS; p += 256) {
        int Ri = p / QS, Qi = p - Ri * QS;
        bool valid = ((unsigned)(tr + Ri - 1) < (unsigned)(NSZ - 1)) &&
                     ((unsigned)(tq + Qi - 1) < (unsigned)(NSZ - 1));
        float msk = valid ? 1.0f : 0.0f;
        #define SVL(rr, qq, c) sv[(((rr) * HS) + (qq)) * 3 + (c)]
        float ax0 = SVL(Ri,   Qi,   0), ay0 = SVL(Ri,   Qi,   1), az0 = SVL(Ri,   Qi,   2);
        float bx  = SVL(Ri,   Qi+1, 0), by  = SVL(Ri,   Qi+1, 1), bz  = SVL(Ri,   Qi+1, 2);
        float cx  = SVL(Ri+1, Qi,   0), cy  = SVL(Ri+1, Qi,   1), cz  = SVL(Ri+1, Qi,   2);
        float dx  = SVL(Ri+1, Qi+1, 0), dy  = SVL(Ri+1, Qi+1, 1), dz  = SVL(Ri+1, Qi+1, 2);
        #undef SVL

        // tri0: (a, b, c)
        {
            float e1x = bx - ax0, e1y = by - ay0, e1z = bz - az0;
            float e2x = cx - ax0, e2y = cy - ay0, e2z = cz - az0;
            float nx = e1y * e2z - e1z * e2y;
            float ny = e1z * e2x - e1x * e2z;
            float nz = e1x * e2y - e1y * e2x;
            float d  = fmaxf(nx * nx + ny * ny + nz * nz, 1e-24f);
            float r  = fast_rsqrt(d) * msk;
            tn0[p * 3 + 0] = nx * r;
            tn0[p * 3 + 1] = ny * r;
            tn0[p * 3 + 2] = nz * r;
        }
        // tri1: (b, d, c)
        {
            float e1x = dx - bx, e1y = dy - by, e1z = dz - bz;
            float e2x = cx - bx, e2y = cy - by, e2z = cz - bz;
            float nx = e1y * e2z - e1z * e2y;
            float ny = e1z * e2x - e1x * e2z;
            float nz = e1x * e2y - e1y * e2x;
            float d  = fmaxf(nx * nx + ny * ny + nz * nz, 1e-24f);
            float r  = fast_rsqrt(d) * msk;
            tn1[p * 3 + 0] = nx * r;
            tn1[p * 3 + 1] = ny * r;
            tn1[p * 3 + 2] = nz * r;
        }
    }
    __syncthreads();

    // phase 2: vertex normal = normalize( sum of 6 adjacent tri normals )
    // vertex local (r,q) -> tn0 at quads (r+1,q+1),(r+1,q),(r,q+1)
    //                       tn1 at quads (r+1,q),(r,q),(r,q+1)
    float sg = (f == 1 || f == 2 || f == 5) ? 1.0f : -1.0f;
    for (int p = threadIdx.x; p < TS * TS; p += 256) {
        int r = p >> 5, q = p & 31;
        int q00 = ((r    ) * QS + (q    )) * 3;   // (r, q)
        int q01 = ((r    ) * QS + (q + 1)) * 3;   // (r, q+1)
        int q10 = ((r + 1) * QS + (q    )) * 3;   // (r+1, q)
        int q11 = ((r + 1) * QS + (q + 1)) * 3;   // (r+1, q+1)

        float ax = tn0[q11 + 0] + tn0[q10 + 0] + tn0[q01 + 0]
                 + tn1[q10 + 0] + tn1[q00 + 0] + tn1[q01 + 0];
        float ay = tn0[q11 + 1] + tn0[q10 + 1] + tn0[q01 + 1]
                 + tn1[q10 + 1] + tn1[q00 + 1] + tn1[q01 + 1];
        float az = tn0[q11 + 2] + tn0[q10 + 2] + tn0[q01 + 2]
                 + tn1[q10 + 2] + tn1[q00 + 2] + tn1[q01 + 2];

        float d  = fmaxf(ax * ax + ay * ay + az * az, 1e-24f);
        float rs = fast_rsqrt(d) * sg;
        int gi = (f * (NSZ * NSZ) + (tr + r) * NSZ + (tq + q)) * 3;
        out2[gi + 0] = ax * rs;
        out2[gi + 1] = ay * rs;
        out2[gi + 2] = az * rs;
    }
}

extern "C" void kernel_launch(void* const* d_in, const int* in_sizes, int n_in,
                              void* d_out, int out_size, void* d_ws, size_t ws_size,
                              hipStream_t stream) {
    const float* vrt = (const float*)d_in[0];
    const float* nrm = (const float*)d_in[1];
    const float* ps  = (const float*)d_in[2];

    float* out0 = (float*)d_out;                 // vert:    6*512*512*3
    float* out1 = out0 + (size_t)NPIX * 3;       // faces:   NFACE*3
    float* out2 = out1 + (size_t)NFACE * 3;      // normals: 6*512*512*3

    k_all<<<NVB + NFB, 256, 0, stream>>>(vrt, nrm, ps, out0, out1, out2);
}